// Round 11
// baseline (198.380 us; speedup 1.0000x reference)
//
#include <hip/hip_runtime.h>
#include <math.h>

// ---------------------------------------------------------------------------
// NODE SEIAR, round 11 — fused; barrier + packed plain-load sweeps.
//  * Numerics IDENTICAL to r10 (absmax 1.2636e-5): Tsit5-h4 transient coarse
//    [0,256] + RK4-h4 post-peak coarse + RK4-h1 fine; same bounds.
//  * r10 post-mortem: cycle model closed — wall = last block's replay chain
//    (~64 T5 + ~191 RK4 steps). Measured step cost ~1.6-2x the chain+issue
//    floor; the excess is per-row readiness checks (3 scalar ATOMIC loads +
//    cmp + branch + respin structure defeating pipelining).
//  * Fix: producers finish ALL 2443 beta evals (~2 rounds, ~2us), signal via
//    fetch_add(RELEASE, AGENT) [emits L2 writeback]; integrators spin, then
//    one ACQUIRE agent load [invalidates local L1+L2 -> no stale poison
//    lines cross-XCD], then sweeps use plain float4 loads of PACKED rows:
//    rowF[i]={b(i),b(i+.5),b(i+1),pad}, rowC[j]={b(256+4j),+2,+4,pad},
//    rowT stride-8 Tsit5 rows. Zero checks/branches in the step loops.
// ---------------------------------------------------------------------------

#define NCHUNK 32
#define NTOTAL 1280     // 5 blocks/CU x 256 CU, all co-resident
#define NPROD  (NTOTAL - NCHUNK)
#define TS     64       // Tsit5-h4 transient steps (covers [0,256])
#define BURN_MAX_POLLS 16384

// producer work sections
#define NT5R   66                  // Tsit5 rows produced (64 + 2 pad)
#define NBI    1024                // beta(i), i in [0,1024)
#define NBH    1023                // beta(i+0.5), i in [0,1023)
#define TTOTAL (NT5R * 6 + NBI + NBH)   // 2443 evals

// ws row allocations (rows)
#define ROWT_ALLOC 68
#define ROWC_ALLOC 200
#define ROWF_ALLOC 1032

// Tsit5 tableau
#define A21f 0.161f
#define A31f -0.008480655492356989f
#define A32f 0.335480655492357f
#define A41f 2.8971530571054935f
#define A42f -6.359448489975075f
#define A43f 4.3622954328695815f
#define A51f 5.325864828439257f
#define A52f -11.748883564062828f
#define A53f 7.4955393428898365f
#define A54f -0.09249506636175525f
#define A61f 5.86145544294642f
#define A62f -12.92096931784711f
#define A63f 8.159367898576159f
#define A64f -0.071584973281401f
#define A65f -0.028269050394068383f
#define B1f 0.09646076681806523f
#define B2f 0.01f
#define B3f 0.4798896504144996f
#define B4f 1.379008574103742f
#define B5f -3.290069515436081f
#define B6f 2.324710524099774f

typedef float v2f __attribute__((ext_vector_type(2)));
__device__ __forceinline__ v2f vfma(v2f a, v2f b, v2f c) {
    return __builtin_elementwise_fma(a, b, c);
}
__device__ __forceinline__ v2f splat2(float x) { return (v2f){x, x}; }

struct Bounds { int s[NCHUNK + 1]; };

__device__ const float g_cstage[6] = {
    0.0f, 0.161f, 0.327f, 0.9f, 0.9800255409045097f, 1.0f};

__device__ __forceinline__ float softplus_f(float x) {
    return fmaxf(x, 0.0f) + log1pf(expf(-fabsf(x)));
}
__device__ __forceinline__ int imin(int a, int b) { return a < b ? a : b; }

// SEIAR constants
#define cKK  0.526f
#define cAA  0.244f
#define cII  0.244f
#define cPKK ((float)(0.667 * 0.526))
#define cQKK ((float)((1.0 - 0.667) * 0.526))
#define cFAA ((float)(0.98 * 0.244))

__device__ __forceinline__ void rhs2(v2f zSE, v2f zIA, float b,
                                     v2f& kSE, v2f& kIA, float& kR) {
    float S = zSE.x, E = zSE.y, I = zIA.x, A = zIA.y;
    float LL = fmaf(0.5f, I, A);
    float T  = (b * S) * LL;
    kSE = (v2f){-T, fmaf(-cKK, E, T)};
    kIA = (v2f){fmaf(cPKK, E, -cAA * I), fmaf(cQKK, E, -cII * A)};
    kR  = fmaf(cFAA, I, cII * A);
}

struct Tab2 {
    v2f a21,a31,a32,a41,a42,a43,a51,a52,a53,a54;
    v2f a61,a62,a63,a64,a65,b1,b2,b3,b4,b5,b6;
};
__device__ __forceinline__ Tab2 make_tab2(float h) {
    Tab2 t;
    t.a21=splat2(A21f*h); t.a31=splat2(A31f*h); t.a32=splat2(A32f*h);
    t.a41=splat2(A41f*h); t.a42=splat2(A42f*h); t.a43=splat2(A43f*h);
    t.a51=splat2(A51f*h); t.a52=splat2(A52f*h); t.a53=splat2(A53f*h);
    t.a54=splat2(A54f*h); t.a61=splat2(A61f*h); t.a62=splat2(A62f*h);
    t.a63=splat2(A63f*h); t.a64=splat2(A64f*h); t.a65=splat2(A65f*h);
    t.b1=splat2(B1f*h); t.b2=splat2(B2f*h); t.b3=splat2(B3f*h);
    t.b4=splat2(B4f*h); t.b5=splat2(B5f*h); t.b6=splat2(B6f*h);
    return t;
}

#define FOLD(dSE,dIA,dR, c, kSE,kIA,kR, pSE,pIA,pR) \
    dSE = vfma(T.c, kSE, pSE); dIA = vfma(T.c, kIA, pIA); \
    dR  = fmaf(T.c.x, kR, pR);

// Tsit5 step, newest-k-last (bit-identical to r10).
__device__ __forceinline__ void t5_step(v2f& zSE, v2f& zIA, float& zR,
                                        const Tab2& T, const float bc[6]) {
    v2f k1SE,k1IA,k2SE,k2IA,k3SE,k3IA,k4SE,k4IA,k5SE,k5IA,k6SE,k6IA;
    float k1R,k2R,k3R,k4R,k5R,k6R;
    v2f tSE,tIA,pSE,pIA; float tR,pR;

    rhs2(zSE,zIA,bc[0],k1SE,k1IA,k1R);
    FOLD(tSE,tIA,tR, a21, k1SE,k1IA,k1R, zSE,zIA,zR);
    rhs2(tSE,tIA,bc[1],k2SE,k2IA,k2R);
    FOLD(pSE,pIA,pR, a31, k1SE,k1IA,k1R, zSE,zIA,zR);
    FOLD(tSE,tIA,tR, a32, k2SE,k2IA,k2R, pSE,pIA,pR);
    rhs2(tSE,tIA,bc[2],k3SE,k3IA,k3R);
    FOLD(pSE,pIA,pR, a41, k1SE,k1IA,k1R, zSE,zIA,zR);
    FOLD(pSE,pIA,pR, a42, k2SE,k2IA,k2R, pSE,pIA,pR);
    FOLD(tSE,tIA,tR, a43, k3SE,k3IA,k3R, pSE,pIA,pR);
    rhs2(tSE,tIA,bc[3],k4SE,k4IA,k4R);
    FOLD(pSE,pIA,pR, a51, k1SE,k1IA,k1R, zSE,zIA,zR);
    FOLD(pSE,pIA,pR, a52, k2SE,k2IA,k2R, pSE,pIA,pR);
    FOLD(pSE,pIA,pR, a53, k3SE,k3IA,k3R, pSE,pIA,pR);
    FOLD(tSE,tIA,tR, a54, k4SE,k4IA,k4R, pSE,pIA,pR);
    rhs2(tSE,tIA,bc[4],k5SE,k5IA,k5R);
    FOLD(pSE,pIA,pR, a61, k1SE,k1IA,k1R, zSE,zIA,zR);
    FOLD(pSE,pIA,pR, a62, k2SE,k2IA,k2R, pSE,pIA,pR);
    FOLD(pSE,pIA,pR, a63, k3SE,k3IA,k3R, pSE,pIA,pR);
    FOLD(pSE,pIA,pR, a64, k4SE,k4IA,k4R, pSE,pIA,pR);
    FOLD(tSE,tIA,tR, a65, k5SE,k5IA,k5R, pSE,pIA,pR);
    rhs2(tSE,tIA,bc[5],k6SE,k6IA,k6R);
    FOLD(pSE,pIA,pR, b1, k1SE,k1IA,k1R, zSE,zIA,zR);
    FOLD(pSE,pIA,pR, b2, k2SE,k2IA,k2R, pSE,pIA,pR);
    FOLD(pSE,pIA,pR, b3, k3SE,k3IA,k3R, pSE,pIA,pR);
    FOLD(pSE,pIA,pR, b4, k4SE,k4IA,k4R, pSE,pIA,pR);
    FOLD(pSE,pIA,pR, b5, k5SE,k5IA,k5R, pSE,pIA,pR);
    FOLD(zSE,zIA,zR, b6, k6SE,k6IA,k6R, pSE,pIA,pR);
}

// RK4 step (bit-identical to r10).
__device__ __forceinline__ void rk4_step(v2f& zSE, v2f& zIA, float& zR,
                                         v2f h2v, v2f hv, v2f h6v,
                                         float b0, float bm, float b1) {
    v2f k1SE,k1IA,k2SE,k2IA,k3SE,k3IA,k4SE,k4IA;
    float k1R,k2R,k3R,k4R;
    v2f tSE,tIA; float tR;
    const v2f two = splat2(2.0f);

    rhs2(zSE,zIA,b0,k1SE,k1IA,k1R);
    tSE=vfma(h2v,k1SE,zSE); tIA=vfma(h2v,k1IA,zIA); tR=fmaf(h2v.x,k1R,zR);
    rhs2(tSE,tIA,bm,k2SE,k2IA,k2R);
    tSE=vfma(h2v,k2SE,zSE); tIA=vfma(h2v,k2IA,zIA); tR=fmaf(h2v.x,k2R,zR);
    rhs2(tSE,tIA,bm,k3SE,k3IA,k3R);
    tSE=vfma(hv,k3SE,zSE);  tIA=vfma(hv,k3IA,zIA);  tR=fmaf(hv.x,k3R,zR);
    v2f PSE = vfma(two, k2SE + k3SE, k1SE);
    v2f PIA = vfma(two, k2IA + k3IA, k1IA);
    float PR = fmaf(2.0f, k2R + k3R, k1R);
    rhs2(tSE,tIA,b1,k4SE,k4IA,k4R);
    zSE = vfma(h6v, PSE + k4SE, zSE);
    zIA = vfma(h6v, PIA + k4IA, zIA);
    zR  = fmaf(h6v.x, PR + k4R, zR);
}

__global__ __launch_bounds__(64, 1) void fused_kernel(
    const float* __restrict__ ts,
    const float* __restrict__ state_vec,
    const float* __restrict__ w_in, const float* __restrict__ b_in,
    const float* __restrict__ w_h,  const float* __restrict__ b_h,
    const float* __restrict__ w_out, const float* __restrict__ b_out,
    unsigned int* __restrict__ prod_done, float* __restrict__ done_arr,
    float* __restrict__ rowT, float4* __restrict__ rowC,
    float4* __restrict__ rowF, float* __restrict__ out,
    Bounds B)
{
    int b    = blockIdx.x;
    int lane = threadIdx.x;

    if (b >= NCHUNK) {
        // ================= producer, then barrier-add, then burn ==========
        int p = b - NCHUNK;
        float t0g = ts[0], hf = ts[1] - ts[0];
        float wi = w_in[lane], bi_ = b_in[lane];
        float bhh = b_h[lane], wo = w_out[lane];
        float bo = b_out[0];
        const float* __restrict__ wr = w_h + (lane << 6);
        float* rowCf = (float*)rowC;
        float* rowFf = (float*)rowF;

        for (int e = p; e < TTOTAL; e += NPROD) {
            float t;
            if (e < NT5R * 6) {
                int row = e / 6, st = e - row * 6;
                t = t0g + (4.0f * row + 4.0f * g_cstage[st]) * hf;
            } else if (e < NT5R * 6 + NBI) {
                int i = e - NT5R * 6;
                t = t0g + (float)i * hf;
            } else {
                int i = e - NT5R * 6 - NBI;
                t = t0g + ((float)i + 0.5f) * hf;
            }
            float h1 = softplus_f(fmaf(wi, t, bi_));
            float acc = bhh;
#pragma unroll
            for (int k = 0; k < 64; ++k)
                acc = fmaf(wr[k], __shfl(h1, k, 64), acc);
            float h2 = softplus_f(acc);
            float pr = wo * h2;
#pragma unroll
            for (int off = 32; off > 0; off >>= 1)
                pr += __shfl_down(pr, off, 64);
            if (lane == 0) {
                float o  = pr + bo;
                float bb = 1.0f / (1.0f + expf(-1e-4f * o));
                if (e < NT5R * 6) {
                    rowT[(e / 6) * 8 + (e % 6)] = bb;
                } else if (e < NT5R * 6 + NBI) {
                    int i = e - NT5R * 6;               // beta(i)
                    if (i < 1023) rowFf[i * 4 + 0] = bb;
                    if (i >= 1)   rowFf[(i - 1) * 4 + 2] = bb;
                    if (i >= 256 && (i & 1) == 0) {
                        int d = i - 256;
                        int j = d >> 2;
                        if ((d & 3) == 0) {
                            if (j < ROWC_ALLOC) rowCf[j * 4 + 0] = bb;
                            if (j >= 1)         rowCf[(j - 1) * 4 + 2] = bb;
                        } else {
                            if (j < ROWC_ALLOC) rowCf[j * 4 + 1] = bb;
                        }
                    }
                } else {
                    int i = e - NT5R * 6 - NBI;         // beta(i+0.5)
                    rowFf[i * 4 + 1] = bb;
                }
            }
        }
        // completion signal: RELEASE agent-scope (drains + L2 writeback)
        if (lane == 0)
            __hip_atomic_fetch_add(prod_done, 1u, __ATOMIC_RELEASE,
                                   __HIP_MEMORY_SCOPE_AGENT);

        // burn: keep clock up until integrators finish (one coalesced poll)
        float x[8];
#pragma unroll
        for (int j = 0; j < 8; ++j) x[j] = 1.0f + (float)(lane + j) * 1e-12f;
        for (int outer = 0; outer < BURN_MAX_POLLS; ++outer) {
            for (int i2 = 0; i2 < 40; ++i2) {
#pragma unroll
                for (int j = 0; j < 8; ++j)
                    x[j] = fmaf(x[j], 0.99999988f, 1e-9f);
            }
            float f = __hip_atomic_load(done_arr + (lane & 31),
                                        __ATOMIC_RELAXED,
                                        __HIP_MEMORY_SCOPE_AGENT);
            if (__all(f == 1.0f)) break;
        }
        float r = 0.0f;
#pragma unroll
        for (int j = 0; j < 8; ++j) r += x[j];
        if (r == 123456.0f) done_arr[63] = r;   // unprovable guard, no DCE
        return;
    }

    // ================= integrator block b (lane 0 only) =================
    if (lane != 0) return;

    int start = B.s[b];
    int end   = B.s[b + 1];
    int nf    = end - start;
    float hf  = ts[1] - ts[0];

    // z0 = softmax(state_vec)  (independent of ws; done before barrier)
    v2f zSE, zIA; float zR;
    {
        float v[5], zz[5];
#pragma unroll
        for (int s = 0; s < 5; ++s) v[s] = state_vec[s];
        float m = v[0];
#pragma unroll
        for (int s = 1; s < 5; ++s) m = fmaxf(m, v[s]);
        float sum = 0.0f;
#pragma unroll
        for (int s = 0; s < 5; ++s) { zz[s] = expf(v[s] - m); sum += zz[s]; }
        float inv = 1.0f / sum;
#pragma unroll
        for (int s = 0; s < 5; ++s) zz[s] *= inv;
        zSE = (v2f){zz[0], zz[1]}; zIA = (v2f){zz[2], zz[3]}; zR = zz[4];
        if (b == 0) {
#pragma unroll
            for (int s = 0; s < 5; ++s) out[s] = zz[s];
        }
    }

    // barrier: wait for ALL producers, then ACQUIRE (invalidates L1+L2 ->
    // subsequent plain loads fetch fresh data; no stale poison lines)
    while (__hip_atomic_load(prod_done, __ATOMIC_RELAXED,
                             __HIP_MEMORY_SCOPE_AGENT) < NPROD) {}
    (void)__hip_atomic_load(prod_done, __ATOMIC_ACQUIRE,
                            __HIP_MEMORY_SCOPE_AGENT);

    if (nf > 0) {
        int nc = start / 4;
        int nT = imin(nc, TS);
        int nR = nc - nT;

        // ---- Tsit5-h4 transient replay: plain vector loads, rot-2 ----
        if (nT > 0) {
            Tab2 T = make_tab2(4.0f * hf);
            float4 q0 = *(const float4*)(rowT);
            float2 s0 = *(const float2*)(rowT + 4);
            float4 q1 = *(const float4*)(rowT + 8);
            float2 s1 = *(const float2*)(rowT + 12);
            int i = 0;
            for (; i + 2 <= nT; i += 2) {
                float bc[6] = {q0.x,q0.y,q0.z,q0.w,s0.x,s0.y};
                q0 = *(const float4*)(rowT + (i + 2) * 8);
                s0 = *(const float2*)(rowT + (i + 2) * 8 + 4);
                t5_step(zSE, zIA, zR, T, bc);
                float bd[6] = {q1.x,q1.y,q1.z,q1.w,s1.x,s1.y};
                q1 = *(const float4*)(rowT + (i + 3) * 8);
                s1 = *(const float2*)(rowT + (i + 3) * 8 + 4);
                t5_step(zSE, zIA, zR, T, bd);
            }
            if (i < nT) {
                float bc[6] = {q0.x,q0.y,q0.z,q0.w,s0.x,s0.y};
                t5_step(zSE, zIA, zR, T, bc);
            }
        }

        // ---- RK4-h4 post-peak replay: float4 rows, rot-4 ----
        if (nR > 0) {
            v2f h2v = splat2(2.0f * hf), hv = splat2(4.0f * hf),
                h6v = splat2(4.0f * hf / 6.0f);
            float4 c0 = rowC[0], c1 = rowC[1], c2 = rowC[2], c3 = rowC[3];
            int j = 0;
            for (; j + 4 <= nR; j += 4) {
                float4 u;
                u = c0; c0 = rowC[j + 4];
                rk4_step(zSE,zIA,zR,h2v,hv,h6v,u.x,u.y,u.z);
                u = c1; c1 = rowC[j + 5];
                rk4_step(zSE,zIA,zR,h2v,hv,h6v,u.x,u.y,u.z);
                u = c2; c2 = rowC[j + 6];
                rk4_step(zSE,zIA,zR,h2v,hv,h6v,u.x,u.y,u.z);
                u = c3; c3 = rowC[j + 7];
                rk4_step(zSE,zIA,zR,h2v,hv,h6v,u.x,u.y,u.z);
            }
            if (j < nR) { rk4_step(zSE,zIA,zR,h2v,hv,h6v,c0.x,c0.y,c0.z); j++; }
            if (j < nR) { rk4_step(zSE,zIA,zR,h2v,hv,h6v,c1.x,c1.y,c1.z); j++; }
            if (j < nR) { rk4_step(zSE,zIA,zR,h2v,hv,h6v,c2.x,c2.y,c2.z); j++; }
        }

        // ---- fine RK4-h1 sweep: float4 rows, rot-4, scalar stores ----
        {
            v2f h2v = splat2(0.5f * hf), hv = splat2(hf),
                h6v = splat2(hf * (1.0f / 6.0f));
            const float4* RF = rowF + start;
            float4 r0 = RF[0], r1 = RF[1], r2 = RF[2], r3 = RF[3];
            int i = 0;
#define FSTORE(ii) { \
            float* op = out + (size_t)(start + (ii) + 1) * 5; \
            op[0]=zSE.x; op[1]=zSE.y; op[2]=zIA.x; op[3]=zIA.y; op[4]=zR; }
            for (; i + 4 <= nf; i += 4) {
                float4 u;
                u = r0; r0 = RF[i + 4];
                rk4_step(zSE,zIA,zR,h2v,hv,h6v,u.x,u.y,u.z); FSTORE(i)
                u = r1; r1 = RF[i + 5];
                rk4_step(zSE,zIA,zR,h2v,hv,h6v,u.x,u.y,u.z); FSTORE(i + 1)
                u = r2; r2 = RF[i + 6];
                rk4_step(zSE,zIA,zR,h2v,hv,h6v,u.x,u.y,u.z); FSTORE(i + 2)
                u = r3; r3 = RF[i + 7];
                rk4_step(zSE,zIA,zR,h2v,hv,h6v,u.x,u.y,u.z); FSTORE(i + 3)
            }
            if (i < nf) { rk4_step(zSE,zIA,zR,h2v,hv,h6v,r0.x,r0.y,r0.z);
                          FSTORE(i) i++; }
            if (i < nf) { rk4_step(zSE,zIA,zR,h2v,hv,h6v,r1.x,r1.y,r1.z);
                          FSTORE(i) i++; }
            if (i < nf) { rk4_step(zSE,zIA,zR,h2v,hv,h6v,r2.x,r2.y,r2.z);
                          FSTORE(i) i++; }
#undef FSTORE
        }
    }

    __hip_atomic_store(done_arr + b, 1.0f, __ATOMIC_RELAXED,
                       __HIP_MEMORY_SCOPE_AGENT);
}

extern "C" void kernel_launch(void* const* d_in, const int* in_sizes, int n_in,
                              void* d_out, int out_size, void* d_ws, size_t ws_size,
                              hipStream_t stream)
{
    // 0 y0_ignored(5) 1 ts(1024) 2 state_vec(5) 3 w_in(64) 4 b_in(64)
    // 5 w_h(4096) 6 b_h(64) 7 w_out(64) 8 b_out(1) 9 scales(5)  [all f32]
    const float* ts        = (const float*)d_in[1];
    const float* state_vec = (const float*)d_in[2];
    const float* w_in      = (const float*)d_in[3];
    const float* b_in      = (const float*)d_in[4];
    const float* w_h       = (const float*)d_in[5];
    const float* b_h       = (const float*)d_in[6];
    const float* w_out     = (const float*)d_in[7];
    const float* b_out     = (const float*)d_in[8];
    float* out = (float*)d_out;

    int n_t   = in_sizes[1];
    int n_int = n_t - 1;                          // 1023

    // r10 bounds verbatim (same boundaries -> identical numerics).
    auto costR = [](float s) {
        float a = s < 256.f ? s : 256.f;
        float c = s > 256.f ? s - 256.f : 0.f;
        return 0.25f * a + 0.15f * c;
    };
    auto cover = [&](float D) {
        float s = 0.f;
        for (int bb = 0; bb < NCHUNK; ++bb) {
            float f = (D - costR(s)) / 0.6f;
            int fi = ((int)(f / 4.f)) * 4;
            if (fi < 4) fi = 4;
            s += (float)fi;
        }
        return (int)s;
    };
    float lo = 4.f, hi = 1200.f;
    for (int it = 0; it < 48; ++it) {
        float mid = 0.5f * (lo + hi);
        if (cover(mid) >= n_int) hi = mid; else lo = mid;
    }
    float D = hi;
    Bounds B;
    {
        float s = 0.f; B.s[0] = 0;
        for (int bb = 0; bb < NCHUNK; ++bb) {
            float f = (D - costR(s)) / 0.6f;
            int fi = ((int)(f / 4.f)) * 4;
            if (fi < 4) fi = 4;
            s += (float)fi;
            int si = (int)s;
            if (si > n_int) si = n_int;
            B.s[bb + 1] = si;
            s = (float)si;
        }
        B.s[NCHUNK] = n_int;
    }

    // Workspace layout (16B-aligned sections):
    //   ctrl: prod_done (u32) + pad + done_arr (64 f)  = 68 floats
    //   rowT: ROWT_ALLOC * 8 f ; rowC: ROWC_ALLOC * 4 f ; rowF: ROWF_ALLOC * 4 f
    float* ctrl  = (float*)d_ws;
    unsigned int* prod_done = (unsigned int*)ctrl;
    float* done_arr = ctrl + 4;
    float* rowT  = ctrl + 68;
    float4* rowC = (float4*)(rowT + (size_t)ROWT_ALLOC * 8);
    float4* rowF = rowC + ROWC_ALLOC;

    // zero the control words (poisoned 0xAA otherwise)
    hipMemsetAsync(ctrl, 0, 68 * sizeof(float), stream);

    fused_kernel<<<NTOTAL, 64, 0, stream>>>(
        ts, state_vec, w_in, b_in, w_h, b_h, w_out, b_out,
        prod_done, done_arr, rowT, rowC, rowF, out, B);
}

// Round 12
// 140.032 us; speedup vs baseline: 1.4167x; 1.4167x over previous
//
#include <hip/hip_runtime.h>
#include <math.h>

// ---------------------------------------------------------------------------
// NODE SEIAR, round 12 — fused; DISTRIBUTED barrier + packed plain-load
// sweeps.
//  * Numerics IDENTICAL to r10/r11 (absmax 1.263618e-5): Tsit5-h4 transient
//    coarse [0,256] + RK4-h4 post-peak coarse + RK4-h1 fine; same bounds.
//  * r11 post-mortem: single shared fetch_add counter = 1248 serialized
//    same-line RMWs (+71 KB WRITE_SIZE of line writebacks) -> integrators
//    stalled ~70 us at the barrier. Total VALU work unchanged vs r10 ->
//    pure dead time.
//  * Fix: per-producer RELEASE flag stores (own slot, no RMW, no sharing);
//    integrators poll with all 64 lanes (20 independent loads + __all),
//    then one acquire fence (agent scope) -> all producer plain stores
//    visible (fence-atomic sync; r11 verified the acquire/invalidate path).
//  * Sweeps (r11 verbatim): plain float4 loads of packed rows, zero checks:
//    rowF[i]={b(i),b(i+.5),b(i+1),pad}, rowC[j]={b(256+4j),+2,+4,pad},
//    rowT stride-8 Tsit5 rows.
// ---------------------------------------------------------------------------

#define NCHUNK 32
#define NTOTAL 1280     // 5 blocks/CU x 256 CU, all co-resident
#define NPROD  (NTOTAL - NCHUNK)
#define TS     64       // Tsit5-h4 transient steps (covers [0,256])
#define BURN_MAX_POLLS 16384

// producer work sections
#define NT5R   66                  // Tsit5 rows produced (64 + 2 pad)
#define NBI    1024                // beta(i), i in [0,1024)
#define NBH    1023                // beta(i+0.5), i in [0,1023)
#define TTOTAL (NT5R * 6 + NBI + NBH)   // 2443 evals

// ws row allocations (rows)
#define ROWT_ALLOC 68
#define ROWC_ALLOC 200
#define ROWF_ALLOC 1032

// Tsit5 tableau
#define A21f 0.161f
#define A31f -0.008480655492356989f
#define A32f 0.335480655492357f
#define A41f 2.8971530571054935f
#define A42f -6.359448489975075f
#define A43f 4.3622954328695815f
#define A51f 5.325864828439257f
#define A52f -11.748883564062828f
#define A53f 7.4955393428898365f
#define A54f -0.09249506636175525f
#define A61f 5.86145544294642f
#define A62f -12.92096931784711f
#define A63f 8.159367898576159f
#define A64f -0.071584973281401f
#define A65f -0.028269050394068383f
#define B1f 0.09646076681806523f
#define B2f 0.01f
#define B3f 0.4798896504144996f
#define B4f 1.379008574103742f
#define B5f -3.290069515436081f
#define B6f 2.324710524099774f

typedef float v2f __attribute__((ext_vector_type(2)));
__device__ __forceinline__ v2f vfma(v2f a, v2f b, v2f c) {
    return __builtin_elementwise_fma(a, b, c);
}
__device__ __forceinline__ v2f splat2(float x) { return (v2f){x, x}; }

struct Bounds { int s[NCHUNK + 1]; };

__device__ const float g_cstage[6] = {
    0.0f, 0.161f, 0.327f, 0.9f, 0.9800255409045097f, 1.0f};

__device__ __forceinline__ float softplus_f(float x) {
    return fmaxf(x, 0.0f) + log1pf(expf(-fabsf(x)));
}
__device__ __forceinline__ int imin(int a, int b) { return a < b ? a : b; }

// SEIAR constants
#define cKK  0.526f
#define cAA  0.244f
#define cII  0.244f
#define cPKK ((float)(0.667 * 0.526))
#define cQKK ((float)((1.0 - 0.667) * 0.526))
#define cFAA ((float)(0.98 * 0.244))

__device__ __forceinline__ void rhs2(v2f zSE, v2f zIA, float b,
                                     v2f& kSE, v2f& kIA, float& kR) {
    float S = zSE.x, E = zSE.y, I = zIA.x, A = zIA.y;
    float LL = fmaf(0.5f, I, A);
    float T  = (b * S) * LL;
    kSE = (v2f){-T, fmaf(-cKK, E, T)};
    kIA = (v2f){fmaf(cPKK, E, -cAA * I), fmaf(cQKK, E, -cII * A)};
    kR  = fmaf(cFAA, I, cII * A);
}

struct Tab2 {
    v2f a21,a31,a32,a41,a42,a43,a51,a52,a53,a54;
    v2f a61,a62,a63,a64,a65,b1,b2,b3,b4,b5,b6;
};
__device__ __forceinline__ Tab2 make_tab2(float h) {
    Tab2 t;
    t.a21=splat2(A21f*h); t.a31=splat2(A31f*h); t.a32=splat2(A32f*h);
    t.a41=splat2(A41f*h); t.a42=splat2(A42f*h); t.a43=splat2(A43f*h);
    t.a51=splat2(A51f*h); t.a52=splat2(A52f*h); t.a53=splat2(A53f*h);
    t.a54=splat2(A54f*h); t.a61=splat2(A61f*h); t.a62=splat2(A62f*h);
    t.a63=splat2(A63f*h); t.a64=splat2(A64f*h); t.a65=splat2(A65f*h);
    t.b1=splat2(B1f*h); t.b2=splat2(B2f*h); t.b3=splat2(B3f*h);
    t.b4=splat2(B4f*h); t.b5=splat2(B5f*h); t.b6=splat2(B6f*h);
    return t;
}

#define FOLD(dSE,dIA,dR, c, kSE,kIA,kR, pSE,pIA,pR) \
    dSE = vfma(T.c, kSE, pSE); dIA = vfma(T.c, kIA, pIA); \
    dR  = fmaf(T.c.x, kR, pR);

// Tsit5 step, newest-k-last (bit-identical to r10/r11).
__device__ __forceinline__ void t5_step(v2f& zSE, v2f& zIA, float& zR,
                                        const Tab2& T, const float bc[6]) {
    v2f k1SE,k1IA,k2SE,k2IA,k3SE,k3IA,k4SE,k4IA,k5SE,k5IA,k6SE,k6IA;
    float k1R,k2R,k3R,k4R,k5R,k6R;
    v2f tSE,tIA,pSE,pIA; float tR,pR;

    rhs2(zSE,zIA,bc[0],k1SE,k1IA,k1R);
    FOLD(tSE,tIA,tR, a21, k1SE,k1IA,k1R, zSE,zIA,zR);
    rhs2(tSE,tIA,bc[1],k2SE,k2IA,k2R);
    FOLD(pSE,pIA,pR, a31, k1SE,k1IA,k1R, zSE,zIA,zR);
    FOLD(tSE,tIA,tR, a32, k2SE,k2IA,k2R, pSE,pIA,pR);
    rhs2(tSE,tIA,bc[2],k3SE,k3IA,k3R);
    FOLD(pSE,pIA,pR, a41, k1SE,k1IA,k1R, zSE,zIA,zR);
    FOLD(pSE,pIA,pR, a42, k2SE,k2IA,k2R, pSE,pIA,pR);
    FOLD(tSE,tIA,tR, a43, k3SE,k3IA,k3R, pSE,pIA,pR);
    rhs2(tSE,tIA,bc[3],k4SE,k4IA,k4R);
    FOLD(pSE,pIA,pR, a51, k1SE,k1IA,k1R, zSE,zIA,zR);
    FOLD(pSE,pIA,pR, a52, k2SE,k2IA,k2R, pSE,pIA,pR);
    FOLD(pSE,pIA,pR, a53, k3SE,k3IA,k3R, pSE,pIA,pR);
    FOLD(tSE,tIA,tR, a54, k4SE,k4IA,k4R, pSE,pIA,pR);
    rhs2(tSE,tIA,bc[4],k5SE,k5IA,k5R);
    FOLD(pSE,pIA,pR, a61, k1SE,k1IA,k1R, zSE,zIA,zR);
    FOLD(pSE,pIA,pR, a62, k2SE,k2IA,k2R, pSE,pIA,pR);
    FOLD(pSE,pIA,pR, a63, k3SE,k3IA,k3R, pSE,pIA,pR);
    FOLD(pSE,pIA,pR, a64, k4SE,k4IA,k4R, pSE,pIA,pR);
    FOLD(tSE,tIA,tR, a65, k5SE,k5IA,k5R, pSE,pIA,pR);
    rhs2(tSE,tIA,bc[5],k6SE,k6IA,k6R);
    FOLD(pSE,pIA,pR, b1, k1SE,k1IA,k1R, zSE,zIA,zR);
    FOLD(pSE,pIA,pR, b2, k2SE,k2IA,k2R, pSE,pIA,pR);
    FOLD(pSE,pIA,pR, b3, k3SE,k3IA,k3R, pSE,pIA,pR);
    FOLD(pSE,pIA,pR, b4, k4SE,k4IA,k4R, pSE,pIA,pR);
    FOLD(pSE,pIA,pR, b5, k5SE,k5IA,k5R, pSE,pIA,pR);
    FOLD(zSE,zIA,zR, b6, k6SE,k6IA,k6R, pSE,pIA,pR);
}

// RK4 step (bit-identical to r10/r11).
__device__ __forceinline__ void rk4_step(v2f& zSE, v2f& zIA, float& zR,
                                         v2f h2v, v2f hv, v2f h6v,
                                         float b0, float bm, float b1) {
    v2f k1SE,k1IA,k2SE,k2IA,k3SE,k3IA,k4SE,k4IA;
    float k1R,k2R,k3R,k4R;
    v2f tSE,tIA; float tR;
    const v2f two = splat2(2.0f);

    rhs2(zSE,zIA,b0,k1SE,k1IA,k1R);
    tSE=vfma(h2v,k1SE,zSE); tIA=vfma(h2v,k1IA,zIA); tR=fmaf(h2v.x,k1R,zR);
    rhs2(tSE,tIA,bm,k2SE,k2IA,k2R);
    tSE=vfma(h2v,k2SE,zSE); tIA=vfma(h2v,k2IA,zIA); tR=fmaf(h2v.x,k2R,zR);
    rhs2(tSE,tIA,bm,k3SE,k3IA,k3R);
    tSE=vfma(hv,k3SE,zSE);  tIA=vfma(hv,k3IA,zIA);  tR=fmaf(hv.x,k3R,zR);
    v2f PSE = vfma(two, k2SE + k3SE, k1SE);
    v2f PIA = vfma(two, k2IA + k3IA, k1IA);
    float PR = fmaf(2.0f, k2R + k3R, k1R);
    rhs2(tSE,tIA,b1,k4SE,k4IA,k4R);
    zSE = vfma(h6v, PSE + k4SE, zSE);
    zIA = vfma(h6v, PIA + k4IA, zIA);
    zR  = fmaf(h6v.x, PR + k4R, zR);
}

__global__ __launch_bounds__(64, 1) void fused_kernel(
    const float* __restrict__ ts,
    const float* __restrict__ state_vec,
    const float* __restrict__ w_in, const float* __restrict__ b_in,
    const float* __restrict__ w_h,  const float* __restrict__ b_h,
    const float* __restrict__ w_out, const float* __restrict__ b_out,
    float* __restrict__ prod_flags, float* __restrict__ done_arr,
    float* __restrict__ rowT, float4* __restrict__ rowC,
    float4* __restrict__ rowF, float* __restrict__ out,
    Bounds B)
{
    int b    = blockIdx.x;
    int lane = threadIdx.x;

    if (b >= NCHUNK) {
        // ============ producer, then own-slot flag, then burn ============
        int p = b - NCHUNK;
        float t0g = ts[0], hf = ts[1] - ts[0];
        float wi = w_in[lane], bi_ = b_in[lane];
        float bhh = b_h[lane], wo = w_out[lane];
        float bo = b_out[0];
        const float* __restrict__ wr = w_h + (lane << 6);
        float* rowCf = (float*)rowC;
        float* rowFf = (float*)rowF;

        for (int e = p; e < TTOTAL; e += NPROD) {
            float t;
            if (e < NT5R * 6) {
                int row = e / 6, st = e - row * 6;
                t = t0g + (4.0f * row + 4.0f * g_cstage[st]) * hf;
            } else if (e < NT5R * 6 + NBI) {
                int i = e - NT5R * 6;
                t = t0g + (float)i * hf;
            } else {
                int i = e - NT5R * 6 - NBI;
                t = t0g + ((float)i + 0.5f) * hf;
            }
            float h1 = softplus_f(fmaf(wi, t, bi_));
            float acc = bhh;
#pragma unroll
            for (int k = 0; k < 64; ++k)
                acc = fmaf(wr[k], __shfl(h1, k, 64), acc);
            float h2 = softplus_f(acc);
            float pr = wo * h2;
#pragma unroll
            for (int off = 32; off > 0; off >>= 1)
                pr += __shfl_down(pr, off, 64);
            if (lane == 0) {
                float o  = pr + bo;
                float bb = 1.0f / (1.0f + expf(-1e-4f * o));
                if (e < NT5R * 6) {
                    rowT[(e / 6) * 8 + (e % 6)] = bb;
                } else if (e < NT5R * 6 + NBI) {
                    int i = e - NT5R * 6;               // beta(i)
                    if (i < 1023) rowFf[i * 4 + 0] = bb;
                    if (i >= 1)   rowFf[(i - 1) * 4 + 2] = bb;
                    if (i >= 256 && (i & 1) == 0) {
                        int d = i - 256;
                        int j = d >> 2;
                        if ((d & 3) == 0) {
                            if (j < ROWC_ALLOC) rowCf[j * 4 + 0] = bb;
                            if (j >= 1)         rowCf[(j - 1) * 4 + 2] = bb;
                        } else {
                            if (j < ROWC_ALLOC) rowCf[j * 4 + 1] = bb;
                        }
                    }
                } else {
                    int i = e - NT5R * 6 - NBI;         // beta(i+0.5)
                    rowFf[i * 4 + 1] = bb;
                }
            }
        }
        // own-slot completion flag: RELEASE (flushes prior plain stores),
        // no RMW, no line sharing -> no serialization storm (r11 fix).
        if (lane == 0)
            __hip_atomic_store(prod_flags + p, 1.0f, __ATOMIC_RELEASE,
                               __HIP_MEMORY_SCOPE_AGENT);

        // burn: keep clock up until integrators finish (one coalesced poll)
        float x[8];
#pragma unroll
        for (int j = 0; j < 8; ++j) x[j] = 1.0f + (float)(lane + j) * 1e-12f;
        for (int outer = 0; outer < BURN_MAX_POLLS; ++outer) {
            for (int i2 = 0; i2 < 40; ++i2) {
#pragma unroll
                for (int j = 0; j < 8; ++j)
                    x[j] = fmaf(x[j], 0.99999988f, 1e-9f);
            }
            float f = __hip_atomic_load(done_arr + (lane & 31),
                                        __ATOMIC_RELAXED,
                                        __HIP_MEMORY_SCOPE_AGENT);
            if (__all(f == 1.0f)) break;
        }
        float r = 0.0f;
#pragma unroll
        for (int j = 0; j < 8; ++j) r += x[j];
        if (r == 123456.0f) done_arr[63] = r;   // unprovable guard, no DCE
        return;
    }

    // ================= integrator block b =================
    // Wave-parallel distributed barrier: lane L checks flags L, L+64, ...
    // (20 independent relaxed loads in flight), then acquire fence (agent)
    // -> fence-atomic synchronization with every producer's release store.
    {
        bool ready;
        do {
            float m = 1.0f;
            for (int q = lane; q < NPROD; q += 64) {
                float f = __hip_atomic_load(prod_flags + q, __ATOMIC_RELAXED,
                                            __HIP_MEMORY_SCOPE_AGENT);
                m = fminf(m, f);
            }
            ready = __all(m > 0.0f);
        } while (!ready);
        __builtin_amdgcn_fence(__ATOMIC_ACQUIRE, "agent");
    }
    if (lane != 0) return;

    int start = B.s[b];
    int end   = B.s[b + 1];
    int nf    = end - start;
    float hf  = ts[1] - ts[0];

    // z0 = softmax(state_vec)
    v2f zSE, zIA; float zR;
    {
        float v[5], zz[5];
#pragma unroll
        for (int s = 0; s < 5; ++s) v[s] = state_vec[s];
        float m = v[0];
#pragma unroll
        for (int s = 1; s < 5; ++s) m = fmaxf(m, v[s]);
        float sum = 0.0f;
#pragma unroll
        for (int s = 0; s < 5; ++s) { zz[s] = expf(v[s] - m); sum += zz[s]; }
        float inv = 1.0f / sum;
#pragma unroll
        for (int s = 0; s < 5; ++s) zz[s] *= inv;
        zSE = (v2f){zz[0], zz[1]}; zIA = (v2f){zz[2], zz[3]}; zR = zz[4];
        if (b == 0) {
#pragma unroll
            for (int s = 0; s < 5; ++s) out[s] = zz[s];
        }
    }

    if (nf > 0) {
        int nc = start / 4;
        int nT = imin(nc, TS);
        int nR = nc - nT;

        // ---- Tsit5-h4 transient replay: plain vector loads, rot-2 ----
        if (nT > 0) {
            Tab2 T = make_tab2(4.0f * hf);
            float4 q0 = *(const float4*)(rowT);
            float2 s0 = *(const float2*)(rowT + 4);
            float4 q1 = *(const float4*)(rowT + 8);
            float2 s1 = *(const float2*)(rowT + 12);
            int i = 0;
            for (; i + 2 <= nT; i += 2) {
                float bc[6] = {q0.x,q0.y,q0.z,q0.w,s0.x,s0.y};
                q0 = *(const float4*)(rowT + (i + 2) * 8);
                s0 = *(const float2*)(rowT + (i + 2) * 8 + 4);
                t5_step(zSE, zIA, zR, T, bc);
                float bd[6] = {q1.x,q1.y,q1.z,q1.w,s1.x,s1.y};
                q1 = *(const float4*)(rowT + (i + 3) * 8);
                s1 = *(const float2*)(rowT + (i + 3) * 8 + 4);
                t5_step(zSE, zIA, zR, T, bd);
            }
            if (i < nT) {
                float bc[6] = {q0.x,q0.y,q0.z,q0.w,s0.x,s0.y};
                t5_step(zSE, zIA, zR, T, bc);
            }
        }

        // ---- RK4-h4 post-peak replay: float4 rows, rot-4 ----
        if (nR > 0) {
            v2f h2v = splat2(2.0f * hf), hv = splat2(4.0f * hf),
                h6v = splat2(4.0f * hf / 6.0f);
            float4 c0 = rowC[0], c1 = rowC[1], c2 = rowC[2], c3 = rowC[3];
            int j = 0;
            for (; j + 4 <= nR; j += 4) {
                float4 u;
                u = c0; c0 = rowC[j + 4];
                rk4_step(zSE,zIA,zR,h2v,hv,h6v,u.x,u.y,u.z);
                u = c1; c1 = rowC[j + 5];
                rk4_step(zSE,zIA,zR,h2v,hv,h6v,u.x,u.y,u.z);
                u = c2; c2 = rowC[j + 6];
                rk4_step(zSE,zIA,zR,h2v,hv,h6v,u.x,u.y,u.z);
                u = c3; c3 = rowC[j + 7];
                rk4_step(zSE,zIA,zR,h2v,hv,h6v,u.x,u.y,u.z);
            }
            if (j < nR) { rk4_step(zSE,zIA,zR,h2v,hv,h6v,c0.x,c0.y,c0.z); j++; }
            if (j < nR) { rk4_step(zSE,zIA,zR,h2v,hv,h6v,c1.x,c1.y,c1.z); j++; }
            if (j < nR) { rk4_step(zSE,zIA,zR,h2v,hv,h6v,c2.x,c2.y,c2.z); j++; }
        }

        // ---- fine RK4-h1 sweep: float4 rows, rot-4, scalar stores ----
        {
            v2f h2v = splat2(0.5f * hf), hv = splat2(hf),
                h6v = splat2(hf * (1.0f / 6.0f));
            const float4* RF = rowF + start;
            float4 r0 = RF[0], r1 = RF[1], r2 = RF[2], r3 = RF[3];
            int i = 0;
#define FSTORE(ii) { \
            float* op = out + (size_t)(start + (ii) + 1) * 5; \
            op[0]=zSE.x; op[1]=zSE.y; op[2]=zIA.x; op[3]=zIA.y; op[4]=zR; }
            for (; i + 4 <= nf; i += 4) {
                float4 u;
                u = r0; r0 = RF[i + 4];
                rk4_step(zSE,zIA,zR,h2v,hv,h6v,u.x,u.y,u.z); FSTORE(i)
                u = r1; r1 = RF[i + 5];
                rk4_step(zSE,zIA,zR,h2v,hv,h6v,u.x,u.y,u.z); FSTORE(i + 1)
                u = r2; r2 = RF[i + 6];
                rk4_step(zSE,zIA,zR,h2v,hv,h6v,u.x,u.y,u.z); FSTORE(i + 2)
                u = r3; r3 = RF[i + 7];
                rk4_step(zSE,zIA,zR,h2v,hv,h6v,u.x,u.y,u.z); FSTORE(i + 3)
            }
            if (i < nf) { rk4_step(zSE,zIA,zR,h2v,hv,h6v,r0.x,r0.y,r0.z);
                          FSTORE(i) i++; }
            if (i < nf) { rk4_step(zSE,zIA,zR,h2v,hv,h6v,r1.x,r1.y,r1.z);
                          FSTORE(i) i++; }
            if (i < nf) { rk4_step(zSE,zIA,zR,h2v,hv,h6v,r2.x,r2.y,r2.z);
                          FSTORE(i) i++; }
#undef FSTORE
        }
    }

    __hip_atomic_store(done_arr + b, 1.0f, __ATOMIC_RELAXED,
                       __HIP_MEMORY_SCOPE_AGENT);
}

extern "C" void kernel_launch(void* const* d_in, const int* in_sizes, int n_in,
                              void* d_out, int out_size, void* d_ws, size_t ws_size,
                              hipStream_t stream)
{
    // 0 y0_ignored(5) 1 ts(1024) 2 state_vec(5) 3 w_in(64) 4 b_in(64)
    // 5 w_h(4096) 6 b_h(64) 7 w_out(64) 8 b_out(1) 9 scales(5)  [all f32]
    const float* ts        = (const float*)d_in[1];
    const float* state_vec = (const float*)d_in[2];
    const float* w_in      = (const float*)d_in[3];
    const float* b_in      = (const float*)d_in[4];
    const float* w_h       = (const float*)d_in[5];
    const float* b_h       = (const float*)d_in[6];
    const float* w_out     = (const float*)d_in[7];
    const float* b_out     = (const float*)d_in[8];
    float* out = (float*)d_out;

    int n_t   = in_sizes[1];
    int n_int = n_t - 1;                          // 1023

    // r10 bounds verbatim (same boundaries -> identical numerics).
    auto costR = [](float s) {
        float a = s < 256.f ? s : 256.f;
        float c = s > 256.f ? s - 256.f : 0.f;
        return 0.25f * a + 0.15f * c;
    };
    auto cover = [&](float D) {
        float s = 0.f;
        for (int bb = 0; bb < NCHUNK; ++bb) {
            float f = (D - costR(s)) / 0.6f;
            int fi = ((int)(f / 4.f)) * 4;
            if (fi < 4) fi = 4;
            s += (float)fi;
        }
        return (int)s;
    };
    float lo = 4.f, hi = 1200.f;
    for (int it = 0; it < 48; ++it) {
        float mid = 0.5f * (lo + hi);
        if (cover(mid) >= n_int) hi = mid; else lo = mid;
    }
    float D = hi;
    Bounds B;
    {
        float s = 0.f; B.s[0] = 0;
        for (int bb = 0; bb < NCHUNK; ++bb) {
            float f = (D - costR(s)) / 0.6f;
            int fi = ((int)(f / 4.f)) * 4;
            if (fi < 4) fi = 4;
            s += (float)fi;
            int si = (int)s;
            if (si > n_int) si = n_int;
            B.s[bb + 1] = si;
            s = (float)si;
        }
        B.s[NCHUNK] = n_int;
    }

    // Workspace layout (16B-aligned sections, floats):
    //   done_arr  : 64
    //   prod_flags: 1280 (NPROD=1248 used; 0xAA poison < 0 = not ready)
    //   rowT      : ROWT_ALLOC*8
    //   rowC      : ROWC_ALLOC*4
    //   rowF      : ROWF_ALLOC*4
    float* done_arr   = (float*)d_ws;
    float* prod_flags = done_arr + 64;
    float* rowT       = prod_flags + 1280;
    float4* rowC      = (float4*)(rowT + (size_t)ROWT_ALLOC * 8);
    float4* rowF      = rowC + ROWC_ALLOC;

    fused_kernel<<<NTOTAL, 64, 0, stream>>>(
        ts, state_vec, w_in, b_in, w_h, b_h, w_out, b_out,
        prod_flags, done_arr, rowT, rowC, rowF, out, B);
}

// Round 13
// 137.454 us; speedup vs baseline: 1.4432x; 1.0188x over previous
//
#include <hip/hip_runtime.h>
#include <math.h>

// ---------------------------------------------------------------------------
// NODE SEIAR, round 13 — r10 structure + SPARSE burn (clock/power knob).
//  * Numerics IDENTICAL to r10/r11/r12 (absmax 1.263618e-5): Tsit5-h4
//    transient coarse [0,256] + RK4-h4 post-peak coarse + RK4-h1 fine;
//    value-polling zero-barrier overlap (r10 verbatim — best structure:
//    71.7us vs r12 barrier 86us).
//  * r12 post-mortem: barrier waits for slowest of 1248 producers (~14us);
//    polling overlaps production. Barrier path abandoned.
//  * Clock forensics: r4's fixed-iter burn = 131K unambiguous issue-cycles
//    in 119us -> 1.10 GHz during FULL-chip FMA burn = power-throttled floor.
//    Idle (r1-r3): ~0.5-0.8 GHz park. The burn was dragging SCLK DOWN.
//    Fix: only 1/4 of producers burn after producing (~312 waves, ~12% FMA
//    power) — keeps SMU activity ramp engaged with power headroom to boost;
//    exited producers also free issue slots on integrator CUs.
//  * h>4 coarse is provably unstable (lambda=-0.526: Tsit5 bound 3.4 ->
//    h<6.5; RK4 2.78 -> h<5.3), so serial depth ~256+191 is structural.
// ---------------------------------------------------------------------------

#define NCHUNK 32
#define NTOTAL 1280     // 5 blocks/CU x 256 CU, all co-resident
#define NPROD  (NTOTAL - NCHUNK)
#define TS     64       // Tsit5-h4 transient coarse steps (covers [0,256])
#define BURN_MAX_POLLS 16384

// workspace sizes (floats)
#define NI 1032         // beta_int produced count
#define NH 1028         // beta_half produced count
#define NI_ALLOC 1048
#define NH_ALLOC 1040
#define NCT 66          // Tsit5 coarse rows produced (64 + 2 prefetch pads)

// Tsit5 tableau
#define A21f 0.161f
#define A31f -0.008480655492356989f
#define A32f 0.335480655492357f
#define A41f 2.8971530571054935f
#define A42f -6.359448489975075f
#define A43f 4.3622954328695815f
#define A51f 5.325864828439257f
#define A52f -11.748883564062828f
#define A53f 7.4955393428898365f
#define A54f -0.09249506636175525f
#define A61f 5.86145544294642f
#define A62f -12.92096931784711f
#define A63f 8.159367898576159f
#define A64f -0.071584973281401f
#define A65f -0.028269050394068383f
#define B1f 0.09646076681806523f
#define B2f 0.01f
#define B3f 0.4798896504144996f
#define B4f 1.379008574103742f
#define B5f -3.290069515436081f
#define B6f 2.324710524099774f

typedef float v2f __attribute__((ext_vector_type(2)));
__device__ __forceinline__ v2f vfma(v2f a, v2f b, v2f c) {
    return __builtin_elementwise_fma(a, b, c);
}
__device__ __forceinline__ v2f splat2(float x) { return (v2f){x, x}; }

struct Bounds { int s[NCHUNK + 1]; };

__device__ const float g_cstage[6] = {
    0.0f, 0.161f, 0.327f, 0.9f, 0.9800255409045097f, 1.0f};

__device__ __forceinline__ float softplus_f(float x) {
    return fmaxf(x, 0.0f) + log1pf(expf(-fabsf(x)));
}
__device__ __forceinline__ int imin(int a, int b) { return a < b ? a : b; }

// SEIAR constants
#define cKK  0.526f
#define cAA  0.244f
#define cII  0.244f
#define cPKK ((float)(0.667 * 0.526))
#define cQKK ((float)((1.0 - 0.667) * 0.526))
#define cFAA ((float)(0.98 * 0.244))

// Packed RHS: state (S,E),(I,A),R.
__device__ __forceinline__ void rhs2(v2f zSE, v2f zIA, float b,
                                     v2f& kSE, v2f& kIA, float& kR) {
    float S = zSE.x, E = zSE.y, I = zIA.x, A = zIA.y;
    float LL = fmaf(0.5f, I, A);
    float T  = (b * S) * LL;
    kSE = (v2f){-T, fmaf(-cKK, E, T)};
    kIA = (v2f){fmaf(cPKK, E, -cAA * I), fmaf(cQKK, E, -cII * A)};
    kR  = fmaf(cFAA, I, cII * A);
}

struct Tab2 {
    v2f a21,a31,a32,a41,a42,a43,a51,a52,a53,a54;
    v2f a61,a62,a63,a64,a65,b1,b2,b3,b4,b5,b6;
};
__device__ __forceinline__ Tab2 make_tab2(float h) {
    Tab2 t;
    t.a21=splat2(A21f*h); t.a31=splat2(A31f*h); t.a32=splat2(A32f*h);
    t.a41=splat2(A41f*h); t.a42=splat2(A42f*h); t.a43=splat2(A43f*h);
    t.a51=splat2(A51f*h); t.a52=splat2(A52f*h); t.a53=splat2(A53f*h);
    t.a54=splat2(A54f*h); t.a61=splat2(A61f*h); t.a62=splat2(A62f*h);
    t.a63=splat2(A63f*h); t.a64=splat2(A64f*h); t.a65=splat2(A65f*h);
    t.b1=splat2(B1f*h); t.b2=splat2(B2f*h); t.b3=splat2(B3f*h);
    t.b4=splat2(B4f*h); t.b5=splat2(B5f*h); t.b6=splat2(B6f*h);
    return t;
}

#define FOLD(dSE,dIA,dR, c, kSE,kIA,kR, pSE,pIA,pR) \
    dSE = vfma(T.c, kSE, pSE); dIA = vfma(T.c, kIA, pIA); \
    dR  = fmaf(T.c.x, kR, pR);

// Tsit5 step, newest-k-last (bit-identical to r10).
__device__ __forceinline__ void t5_step(v2f& zSE, v2f& zIA, float& zR,
                                        const Tab2& T, const float bc[6]) {
    v2f k1SE,k1IA,k2SE,k2IA,k3SE,k3IA,k4SE,k4IA,k5SE,k5IA,k6SE,k6IA;
    float k1R,k2R,k3R,k4R,k5R,k6R;
    v2f tSE,tIA,pSE,pIA; float tR,pR;

    rhs2(zSE,zIA,bc[0],k1SE,k1IA,k1R);
    FOLD(tSE,tIA,tR, a21, k1SE,k1IA,k1R, zSE,zIA,zR);
    rhs2(tSE,tIA,bc[1],k2SE,k2IA,k2R);
    FOLD(pSE,pIA,pR, a31, k1SE,k1IA,k1R, zSE,zIA,zR);
    FOLD(tSE,tIA,tR, a32, k2SE,k2IA,k2R, pSE,pIA,pR);
    rhs2(tSE,tIA,bc[2],k3SE,k3IA,k3R);
    FOLD(pSE,pIA,pR, a41, k1SE,k1IA,k1R, zSE,zIA,zR);
    FOLD(pSE,pIA,pR, a42, k2SE,k2IA,k2R, pSE,pIA,pR);
    FOLD(tSE,tIA,tR, a43, k3SE,k3IA,k3R, pSE,pIA,pR);
    rhs2(tSE,tIA,bc[3],k4SE,k4IA,k4R);
    FOLD(pSE,pIA,pR, a51, k1SE,k1IA,k1R, zSE,zIA,zR);
    FOLD(pSE,pIA,pR, a52, k2SE,k2IA,k2R, pSE,pIA,pR);
    FOLD(pSE,pIA,pR, a53, k3SE,k3IA,k3R, pSE,pIA,pR);
    FOLD(tSE,tIA,tR, a54, k4SE,k4IA,k4R, pSE,pIA,pR);
    rhs2(tSE,tIA,bc[4],k5SE,k5IA,k5R);
    FOLD(pSE,pIA,pR, a61, k1SE,k1IA,k1R, zSE,zIA,zR);
    FOLD(pSE,pIA,pR, a62, k2SE,k2IA,k2R, pSE,pIA,pR);
    FOLD(pSE,pIA,pR, a63, k3SE,k3IA,k3R, pSE,pIA,pR);
    FOLD(pSE,pIA,pR, a64, k4SE,k4IA,k4R, pSE,pIA,pR);
    FOLD(tSE,tIA,tR, a65, k5SE,k5IA,k5R, pSE,pIA,pR);
    rhs2(tSE,tIA,bc[5],k6SE,k6IA,k6R);
    FOLD(pSE,pIA,pR, b1, k1SE,k1IA,k1R, zSE,zIA,zR);
    FOLD(pSE,pIA,pR, b2, k2SE,k2IA,k2R, pSE,pIA,pR);
    FOLD(pSE,pIA,pR, b3, k3SE,k3IA,k3R, pSE,pIA,pR);
    FOLD(pSE,pIA,pR, b4, k4SE,k4IA,k4R, pSE,pIA,pR);
    FOLD(pSE,pIA,pR, b5, k5SE,k5IA,k5R, pSE,pIA,pR);
    FOLD(zSE,zIA,zR, b6, k6SE,k6IA,k6R, pSE,pIA,pR);
}

// RK4 step (bit-identical to r10).
__device__ __forceinline__ void rk4_step(v2f& zSE, v2f& zIA, float& zR,
                                         v2f h2v, v2f hv, v2f h6v,
                                         float b0, float bm, float b1) {
    v2f k1SE,k1IA,k2SE,k2IA,k3SE,k3IA,k4SE,k4IA;
    float k1R,k2R,k3R,k4R;
    v2f tSE,tIA; float tR;
    const v2f two = splat2(2.0f);

    rhs2(zSE,zIA,b0,k1SE,k1IA,k1R);
    tSE=vfma(h2v,k1SE,zSE); tIA=vfma(h2v,k1IA,zIA); tR=fmaf(h2v.x,k1R,zR);
    rhs2(tSE,tIA,bm,k2SE,k2IA,k2R);
    tSE=vfma(h2v,k2SE,zSE); tIA=vfma(h2v,k2IA,zIA); tR=fmaf(h2v.x,k2R,zR);
    rhs2(tSE,tIA,bm,k3SE,k3IA,k3R);
    tSE=vfma(hv,k3SE,zSE);  tIA=vfma(hv,k3IA,zIA);  tR=fmaf(hv.x,k3R,zR);
    v2f PSE = vfma(two, k2SE + k3SE, k1SE);
    v2f PIA = vfma(two, k2IA + k3IA, k1IA);
    float PR = fmaf(2.0f, k2R + k3R, k1R);
    rhs2(tSE,tIA,b1,k4SE,k4IA,k4R);
    zSE = vfma(h6v, PSE + k4SE, zSE);
    zIA = vfma(h6v, PIA + k4IA, zIA);
    zR  = fmaf(h6v.x, PR + k4R, zR);
}

__device__ __forceinline__ float aload(const float* p) {
    return __hip_atomic_load(p, __ATOMIC_RELAXED, __HIP_MEMORY_SCOPE_AGENT);
}
__device__ __forceinline__ bool ok3(const float v[3]) {
    return (v[0] > 0.0f) && (v[1] > 0.0f) && (v[2] > 0.0f);
}
__device__ __forceinline__ bool ok6(const float v[6]) {
    return (v[0]>0.f)&&(v[1]>0.f)&&(v[2]>0.f)&&(v[3]>0.f)&&(v[4]>0.f)&&(v[5]>0.f);
}
// fine row i: {beta_int[i], beta_half[i], beta_int[i+1]}
__device__ __forceinline__ void loadF(float v[3], const float* bi,
                                      const float* bh, int i) {
    v[0] = aload(bi + i); v[1] = aload(bh + i); v[2] = aload(bi + i + 1);
}
// coarse-RK4 row j: {beta_int[256+4j], [..+2], [..+4]}
__device__ __forceinline__ void loadC(float v[3], const float* bi, int j) {
    const float* p = bi + 256 + 4 * j;
    v[0] = aload(p); v[1] = aload(p + 2); v[2] = aload(p + 4);
}
__device__ __forceinline__ void load6(float v[6], const float* p) {
#pragma unroll
    for (int j = 0; j < 6; ++j) v[j] = aload(p + j);
}

__global__ __launch_bounds__(64, 1) void fused_kernel(
    const float* __restrict__ ts,
    const float* __restrict__ state_vec,
    const float* __restrict__ w_in, const float* __restrict__ b_in,
    const float* __restrict__ w_h,  const float* __restrict__ b_h,
    const float* __restrict__ w_out, const float* __restrict__ b_out,
    float* __restrict__ beta_int, float* __restrict__ beta_half,
    float* __restrict__ beta_cT,
    float* __restrict__ done_arr, float* __restrict__ out,
    Bounds B)
{
    int b    = blockIdx.x;
    int lane = threadIdx.x;

    if (b >= NCHUNK) {
        // ================= producer, then sparse burn =================
        int p = b - NCHUNK;
        const int TtlPair = 2 * NH;                 // interleaved bi/bh
        const int Ttl = NCT * 6 + TtlPair + (NI - NH);
        float t0g = ts[0], hf = ts[1] - ts[0];
        float wi = w_in[lane], bi_ = b_in[lane];
        float bhh = b_h[lane], wo = w_out[lane];
        float bo = b_out[0];
        const float* __restrict__ wr = w_h + (lane << 6);

        for (int e = p; e < Ttl; e += NPROD) {
            float t; float* dst;
            if (e < NCT * 6) {                      // Tsit5 coarse rows first
                int row = e / 6, st = e - row * 6;
                t = t0g + (4.0f * row + 4.0f * g_cstage[st]) * hf;
                dst = beta_cT + row * 8 + st;
            } else if (e < NCT * 6 + TtlPair) {     // bi/bh interleaved by t
                int idx = e - NCT * 6;
                int i = idx >> 1;
                if (idx & 1) { t = t0g + ((float)i + 0.5f) * hf; dst = beta_half + i; }
                else         { t = t0g + (float)i * hf;          dst = beta_int + i;  }
            } else {                                // beta_int tail
                int i = NH + (e - NCT * 6 - TtlPair);
                t = t0g + (float)i * hf; dst = beta_int + i;
            }
            float h1 = softplus_f(fmaf(wi, t, bi_));
            float acc = bhh;
#pragma unroll
            for (int k = 0; k < 64; ++k)
                acc = fmaf(wr[k], __shfl(h1, k, 64), acc);
            float h2 = softplus_f(acc);
            float pr = wo * h2;
#pragma unroll
            for (int off = 32; off > 0; off >>= 1)
                pr += __shfl_down(pr, off, 64);
            if (lane == 0) {
                float o  = pr + bo;
                float bb = 1.0f / (1.0f + expf(-1e-4f * o));   // in (0,1)
                __hip_atomic_store(dst, bb, __ATOMIC_RELAXED,
                                   __HIP_MEMORY_SCOPE_AGENT);
            }
        }

        // SPARSE burn: only 1 in 4 producers keeps burning (~312 waves,
        // ~12% of peak FMA power). Full-width burn power-throttles SCLK to
        // ~1.1 GHz (r4 forensics); sparse burn keeps the SMU active with
        // headroom to boost. Exiting blocks free issue slots on their CU.
        if ((p & 3) != 0) return;

        float x[8];
#pragma unroll
        for (int j = 0; j < 8; ++j) x[j] = 1.0f + (float)(lane + j) * 1e-12f;
        for (int outer = 0; outer < BURN_MAX_POLLS; ++outer) {
            for (int i2 = 0; i2 < 40; ++i2) {
#pragma unroll
                for (int j = 0; j < 8; ++j)
                    x[j] = fmaf(x[j], 0.99999988f, 1e-9f);
            }
            float f = aload(done_arr + (lane & 31));
            if (__all(f == 1.0f)) break;
        }
        float r = 0.0f;
#pragma unroll
        for (int j = 0; j < 8; ++j) r += x[j];
        if (r == 123456.0f) done_arr[63] = r;
        return;
    }

    // ================= integrator block b (lane 0 only) =================
    if (lane != 0) return;

    int start = B.s[b];
    int end   = B.s[b + 1];
    int nf    = end - start;
    float hf  = ts[1] - ts[0];

    // z0 = softmax(state_vec)
    v2f zSE, zIA; float zR;
    {
        float v[5], zz[5];
#pragma unroll
        for (int s = 0; s < 5; ++s) v[s] = state_vec[s];
        float m = v[0];
#pragma unroll
        for (int s = 1; s < 5; ++s) m = fmaxf(m, v[s]);
        float sum = 0.0f;
#pragma unroll
        for (int s = 0; s < 5; ++s) { zz[s] = expf(v[s] - m); sum += zz[s]; }
        float inv = 1.0f / sum;
#pragma unroll
        for (int s = 0; s < 5; ++s) zz[s] *= inv;
        zSE = (v2f){zz[0], zz[1]}; zIA = (v2f){zz[2], zz[3]}; zR = zz[4];
        if (b == 0) {
#pragma unroll
            for (int s = 0; s < 5; ++s) out[s] = zz[s];
        }
    }

    if (nf > 0) {
        int nc = start / 4;
        int nT = imin(nc, TS);
        int nR = nc - nT;

        // ---- Tsit5-h4 transient coarse replay (rows from beta_cT) ----
        if (nT > 0) {
            Tab2 T = make_tab2(4.0f * hf);
            float r0[6], r1[6], bc[6];
            load6(r0, beta_cT);
            load6(r1, beta_cT + 8);
            int i = 0;
            for (; i + 2 <= nT; i += 2) {
                const float* p0 = beta_cT + i * 8;
                while (!ok6(r0)) load6(r0, p0);
#pragma unroll
                for (int j = 0; j < 6; ++j) bc[j] = r0[j];
                load6(r0, p0 + 16);
                t5_step(zSE, zIA, zR, T, bc);
                const float* p1 = p0 + 8;
                while (!ok6(r1)) load6(r1, p1);
#pragma unroll
                for (int j = 0; j < 6; ++j) bc[j] = r1[j];
                load6(r1, p1 + 16);
                t5_step(zSE, zIA, zR, T, bc);
            }
            if (i < nT) {
                const float* p0 = beta_cT + i * 8;
                while (!ok6(r0)) load6(r0, p0);
#pragma unroll
                for (int j = 0; j < 6; ++j) bc[j] = r0[j];
                t5_step(zSE, zIA, zR, T, bc);
            }
        }

        // ---- RK4-h4 post-peak coarse replay (values from beta_int) ----
        if (nR > 0) {
            v2f h2v = splat2(2.0f * hf), hv = splat2(4.0f * hf),
                h6v = splat2(4.0f * hf / 6.0f);
            float r0[3], r1[3], r2[3], r3[3];
            loadC(r0, beta_int, 0); loadC(r1, beta_int, 1);
            loadC(r2, beta_int, 2); loadC(r3, beta_int, 3);
            int j = 0;
#define CSTEP(R, jj) { \
            while (!ok3(R)) loadC(R, beta_int, (jj)); \
            float b0_=R[0], bm_=R[1], b1_=R[2]; \
            loadC(R, beta_int, (jj) + 4); \
            rk4_step(zSE, zIA, zR, h2v, hv, h6v, b0_, bm_, b1_); }
            for (; j + 4 <= nR; j += 4) {
                CSTEP(r0, j) CSTEP(r1, j + 1) CSTEP(r2, j + 2) CSTEP(r3, j + 3)
            }
            if (j < nR) { while(!ok3(r0)) loadC(r0,beta_int,j);
                rk4_step(zSE,zIA,zR,h2v,hv,h6v,r0[0],r0[1],r0[2]); j++; }
            if (j < nR) { while(!ok3(r1)) loadC(r1,beta_int,j);
                rk4_step(zSE,zIA,zR,h2v,hv,h6v,r1[0],r1[1],r1[2]); j++; }
            if (j < nR) { while(!ok3(r2)) loadC(r2,beta_int,j);
                rk4_step(zSE,zIA,zR,h2v,hv,h6v,r2[0],r2[1],r2[2]); j++; }
#undef CSTEP
        }

        // ---- fine RK4-h1 sweep, store every interval ----
        {
            v2f h2v = splat2(0.5f * hf), hv = splat2(hf),
                h6v = splat2(hf / 6.0f);
            float r0[3], r1[3], r2[3], r3[3];
            loadF(r0, beta_int, beta_half, start);
            loadF(r1, beta_int, beta_half, start + 1);
            loadF(r2, beta_int, beta_half, start + 2);
            loadF(r3, beta_int, beta_half, start + 3);
            int i = 0;
#define FSTEP(R, ii) { \
            int gi = start + (ii); \
            while (!ok3(R)) loadF(R, beta_int, beta_half, gi); \
            float b0_=R[0], bm_=R[1], b1_=R[2]; \
            loadF(R, beta_int, beta_half, gi + 4); \
            rk4_step(zSE, zIA, zR, h2v, hv, h6v, b0_, bm_, b1_); \
            float* op = out + (size_t)(gi + 1) * 5; \
            op[0]=zSE.x; op[1]=zSE.y; op[2]=zIA.x; op[3]=zIA.y; op[4]=zR; }
            for (; i + 4 <= nf; i += 4) {
                FSTEP(r0, i) FSTEP(r1, i + 1) FSTEP(r2, i + 2) FSTEP(r3, i + 3)
            }
#define FTAIL(R) { \
            int gi = start + i; \
            while (!ok3(R)) loadF(R, beta_int, beta_half, gi); \
            rk4_step(zSE, zIA, zR, h2v, hv, h6v, R[0], R[1], R[2]); \
            float* op = out + (size_t)(gi + 1) * 5; \
            op[0]=zSE.x; op[1]=zSE.y; op[2]=zIA.x; op[3]=zIA.y; op[4]=zR; i++; }
            if (i < nf) FTAIL(r0)
            if (i < nf) FTAIL(r1)
            if (i < nf) FTAIL(r2)
#undef FSTEP
#undef FTAIL
        }
    }

    __hip_atomic_store(done_arr + b, 1.0f, __ATOMIC_RELAXED,
                       __HIP_MEMORY_SCOPE_AGENT);
}

extern "C" void kernel_launch(void* const* d_in, const int* in_sizes, int n_in,
                              void* d_out, int out_size, void* d_ws, size_t ws_size,
                              hipStream_t stream)
{
    // 0 y0_ignored(5) 1 ts(1024) 2 state_vec(5) 3 w_in(64) 4 b_in(64)
    // 5 w_h(4096) 6 b_h(64) 7 w_out(64) 8 b_out(1) 9 scales(5)  [all f32]
    const float* ts        = (const float*)d_in[1];
    const float* state_vec = (const float*)d_in[2];
    const float* w_in      = (const float*)d_in[3];
    const float* b_in      = (const float*)d_in[4];
    const float* w_h       = (const float*)d_in[5];
    const float* b_h       = (const float*)d_in[6];
    const float* w_out     = (const float*)d_in[7];
    const float* b_out     = (const float*)d_in[8];
    float* out = (float*)d_out;

    int n_t   = in_sizes[1];
    int n_int = n_t - 1;                          // 1023

    // r10 bounds verbatim (same boundaries -> identical numerics).
    auto costR = [](float s) {
        float a = s < 256.f ? s : 256.f;
        float c = s > 256.f ? s - 256.f : 0.f;
        return 0.25f * a + 0.15f * c;
    };
    auto cover = [&](float D) {
        float s = 0.f;
        for (int bb = 0; bb < NCHUNK; ++bb) {
            float f = (D - costR(s)) / 0.6f;
            int fi = ((int)(f / 4.f)) * 4;
            if (fi < 4) fi = 4;
            s += (float)fi;
        }
        return (int)s;
    };
    float lo = 4.f, hi = 1200.f;
    for (int it = 0; it < 48; ++it) {
        float mid = 0.5f * (lo + hi);
        if (cover(mid) >= n_int) hi = mid; else lo = mid;
    }
    float D = hi;
    Bounds B;
    {
        float s = 0.f; B.s[0] = 0;
        for (int bb = 0; bb < NCHUNK; ++bb) {
            float f = (D - costR(s)) / 0.6f;
            int fi = ((int)(f / 4.f)) * 4;
            if (fi < 4) fi = 4;
            s += (float)fi;
            int si = (int)s;
            if (si > n_int) si = n_int;
            B.s[bb + 1] = si;
            s = (float)si;
        }
        B.s[NCHUNK] = n_int;
    }

    // Workspace layout (floats) — r10 verbatim
    float* beta_int  = (float*)d_ws;                       // NI_ALLOC
    float* beta_half = beta_int + NI_ALLOC;                // NH_ALLOC
    float* beta_cT   = beta_half + NH_ALLOC;               // 68 rows * 8
    float* done_arr  = beta_cT + (size_t)68 * 8;           // 64 floats

    fused_kernel<<<NTOTAL, 64, 0, stream>>>(
        ts, state_vec, w_in, b_in, w_h, b_h, w_out, b_out,
        beta_int, beta_half, beta_cT, done_arr, out, B);
}

// Round 15
// 119.256 us; speedup vs baseline: 1.6635x; 1.1526x over previous
//
#include <hip/hip_runtime.h>
#include <math.h>

// ---------------------------------------------------------------------------
// NODE SEIAR, round 15 — all-h4 numerics (r13-proven) + gated checkless
// sweeps (r14 structure, h5 removed).
//  * r14 post-mortem: RK4-h5 post-peak was marginally unstable (bound
//    2.785/5=0.557 vs E-mode 0.526 — 6% margin; ~150 steps amplified a
//    ~1e-5 seed to 0.72). r7/r8's T5-h4 vs T5-h5 (1.5e-8 vs 0.12) is the
//    same law: h=4 IS THE MAX stable coarse step. All coarse = h4.
//  * Numerics == r10/r13 methods: Tsit5-h4 transient [0,256] + RK4-h4
//    post-peak + RK4-h1 fine (absmax ~1.26e-5, fine-transient dominated).
//  * Structure kept from r14 (the actual perf hypothesis, untested there):
//    phase-entry gates (all-lane atomic verify + __all + acquire fence,
//    r12-proven coherence) then PLAIN packed-float4 loads, zero per-step
//    checks. RK4-h4 midpoint beta(t+2) is on the integer grid ->
//    rowC4[j] = {bi[256+4j], bi[258+4j], bi[260+4j], pad}.
//  * Clock locked ~1.05 GHz (r4/r13). Wall = replay cycles; checkless
//    steps are the remaining lever. Floor ~ 64 T5x~300 + 191 RK4x~180 cyc.
// ---------------------------------------------------------------------------

#define NCHUNK 32
#define NTOTAL 1280     // 5 blocks/CU x 256 CU, all co-resident
#define NPROD  (NTOTAL - NCHUNK)
#define BURN_MAX_POLLS 16384

// producer sections (consumption order)
#define NT5R   66                          // Tsit5 rows (64 + 2 pad)
#define TTOTAL (NT5R * 6 + 2 * 1023 + 1)   // + bi/bh interleaved + bi[1023]

// ws row allocs
#define ROWT_ALLOC 68     // stride 8
#define ROWC_ALLOC 200    // float4
#define ROWF_ALLOC 1032   // float4

// Tsit5 tableau
#define A21f 0.161f
#define A31f -0.008480655492356989f
#define A32f 0.335480655492357f
#define A41f 2.8971530571054935f
#define A42f -6.359448489975075f
#define A43f 4.3622954328695815f
#define A51f 5.325864828439257f
#define A52f -11.748883564062828f
#define A53f 7.4955393428898365f
#define A54f -0.09249506636175525f
#define A61f 5.86145544294642f
#define A62f -12.92096931784711f
#define A63f 8.159367898576159f
#define A64f -0.071584973281401f
#define A65f -0.028269050394068383f
#define B1f 0.09646076681806523f
#define B2f 0.01f
#define B3f 0.4798896504144996f
#define B4f 1.379008574103742f
#define B5f -3.290069515436081f
#define B6f 2.324710524099774f

typedef float v2f __attribute__((ext_vector_type(2)));
__device__ __forceinline__ v2f vfma(v2f a, v2f b, v2f c) {
    return __builtin_elementwise_fma(a, b, c);
}
__device__ __forceinline__ v2f splat2(float x) { return (v2f){x, x}; }

struct Bounds { int s[NCHUNK + 1]; };

__device__ const float g_cstage[6] = {
    0.0f, 0.161f, 0.327f, 0.9f, 0.9800255409045097f, 1.0f};

__device__ __forceinline__ float softplus_f(float x) {
    return fmaxf(x, 0.0f) + log1pf(expf(-fabsf(x)));
}
__device__ __forceinline__ int imin(int a, int b) { return a < b ? a : b; }

// SEIAR constants
#define cKK  0.526f
#define cAA  0.244f
#define cII  0.244f
#define cPKK ((float)(0.667 * 0.526))
#define cQKK ((float)((1.0 - 0.667) * 0.526))
#define cFAA ((float)(0.98 * 0.244))

__device__ __forceinline__ void rhs2(v2f zSE, v2f zIA, float b,
                                     v2f& kSE, v2f& kIA, float& kR) {
    float S = zSE.x, E = zSE.y, I = zIA.x, A = zIA.y;
    float LL = fmaf(0.5f, I, A);
    float T  = (b * S) * LL;
    kSE = (v2f){-T, fmaf(-cKK, E, T)};
    kIA = (v2f){fmaf(cPKK, E, -cAA * I), fmaf(cQKK, E, -cII * A)};
    kR  = fmaf(cFAA, I, cII * A);
}

struct Tab2 {
    v2f a21,a31,a32,a41,a42,a43,a51,a52,a53,a54;
    v2f a61,a62,a63,a64,a65,b1,b2,b3,b4,b5,b6;
};
__device__ __forceinline__ Tab2 make_tab2(float h) {
    Tab2 t;
    t.a21=splat2(A21f*h); t.a31=splat2(A31f*h); t.a32=splat2(A32f*h);
    t.a41=splat2(A41f*h); t.a42=splat2(A42f*h); t.a43=splat2(A43f*h);
    t.a51=splat2(A51f*h); t.a52=splat2(A52f*h); t.a53=splat2(A53f*h);
    t.a54=splat2(A54f*h); t.a61=splat2(A61f*h); t.a62=splat2(A62f*h);
    t.a63=splat2(A63f*h); t.a64=splat2(A64f*h); t.a65=splat2(A65f*h);
    t.b1=splat2(B1f*h); t.b2=splat2(B2f*h); t.b3=splat2(B3f*h);
    t.b4=splat2(B4f*h); t.b5=splat2(B5f*h); t.b6=splat2(B6f*h);
    return t;
}

#define FOLD(dSE,dIA,dR, c, kSE,kIA,kR, pSE,pIA,pR) \
    dSE = vfma(T.c, kSE, pSE); dIA = vfma(T.c, kIA, pIA); \
    dR  = fmaf(T.c.x, kR, pR);

// Tsit5 step, newest-k-last (bit-identical to r10/r13).
__device__ __forceinline__ void t5_step(v2f& zSE, v2f& zIA, float& zR,
                                        const Tab2& T, const float bc[6]) {
    v2f k1SE,k1IA,k2SE,k2IA,k3SE,k3IA,k4SE,k4IA,k5SE,k5IA,k6SE,k6IA;
    float k1R,k2R,k3R,k4R,k5R,k6R;
    v2f tSE,tIA,pSE,pIA; float tR,pR;

    rhs2(zSE,zIA,bc[0],k1SE,k1IA,k1R);
    FOLD(tSE,tIA,tR, a21, k1SE,k1IA,k1R, zSE,zIA,zR);
    rhs2(tSE,tIA,bc[1],k2SE,k2IA,k2R);
    FOLD(pSE,pIA,pR, a31, k1SE,k1IA,k1R, zSE,zIA,zR);
    FOLD(tSE,tIA,tR, a32, k2SE,k2IA,k2R, pSE,pIA,pR);
    rhs2(tSE,tIA,bc[2],k3SE,k3IA,k3R);
    FOLD(pSE,pIA,pR, a41, k1SE,k1IA,k1R, zSE,zIA,zR);
    FOLD(pSE,pIA,pR, a42, k2SE,k2IA,k2R, pSE,pIA,pR);
    FOLD(tSE,tIA,tR, a43, k3SE,k3IA,k3R, pSE,pIA,pR);
    rhs2(tSE,tIA,bc[3],k4SE,k4IA,k4R);
    FOLD(pSE,pIA,pR, a51, k1SE,k1IA,k1R, zSE,zIA,zR);
    FOLD(pSE,pIA,pR, a52, k2SE,k2IA,k2R, pSE,pIA,pR);
    FOLD(pSE,pIA,pR, a53, k3SE,k3IA,k3R, pSE,pIA,pR);
    FOLD(tSE,tIA,tR, a54, k4SE,k4IA,k4R, pSE,pIA,pR);
    rhs2(tSE,tIA,bc[4],k5SE,k5IA,k5R);
    FOLD(pSE,pIA,pR, a61, k1SE,k1IA,k1R, zSE,zIA,zR);
    FOLD(pSE,pIA,pR, a62, k2SE,k2IA,k2R, pSE,pIA,pR);
    FOLD(pSE,pIA,pR, a63, k3SE,k3IA,k3R, pSE,pIA,pR);
    FOLD(pSE,pIA,pR, a64, k4SE,k4IA,k4R, pSE,pIA,pR);
    FOLD(tSE,tIA,tR, a65, k5SE,k5IA,k5R, pSE,pIA,pR);
    rhs2(tSE,tIA,bc[5],k6SE,k6IA,k6R);
    FOLD(pSE,pIA,pR, b1, k1SE,k1IA,k1R, zSE,zIA,zR);
    FOLD(pSE,pIA,pR, b2, k2SE,k2IA,k2R, pSE,pIA,pR);
    FOLD(pSE,pIA,pR, b3, k3SE,k3IA,k3R, pSE,pIA,pR);
    FOLD(pSE,pIA,pR, b4, k4SE,k4IA,k4R, pSE,pIA,pR);
    FOLD(pSE,pIA,pR, b5, k5SE,k5IA,k5R, pSE,pIA,pR);
    FOLD(zSE,zIA,zR, b6, k6SE,k6IA,k6R, pSE,pIA,pR);
}

// RK4 step (bit-identical to r10/r13).
__device__ __forceinline__ void rk4_step(v2f& zSE, v2f& zIA, float& zR,
                                         v2f h2v, v2f hv, v2f h6v,
                                         float b0, float bm, float b1) {
    v2f k1SE,k1IA,k2SE,k2IA,k3SE,k3IA,k4SE,k4IA;
    float k1R,k2R,k3R,k4R;
    v2f tSE,tIA; float tR;
    const v2f two = splat2(2.0f);

    rhs2(zSE,zIA,b0,k1SE,k1IA,k1R);
    tSE=vfma(h2v,k1SE,zSE); tIA=vfma(h2v,k1IA,zIA); tR=fmaf(h2v.x,k1R,zR);
    rhs2(tSE,tIA,bm,k2SE,k2IA,k2R);
    tSE=vfma(h2v,k2SE,zSE); tIA=vfma(h2v,k2IA,zIA); tR=fmaf(h2v.x,k2R,zR);
    rhs2(tSE,tIA,bm,k3SE,k3IA,k3R);
    tSE=vfma(hv,k3SE,zSE);  tIA=vfma(hv,k3IA,zIA);  tR=fmaf(hv.x,k3R,zR);
    v2f PSE = vfma(two, k2SE + k3SE, k1SE);
    v2f PIA = vfma(two, k2IA + k3IA, k1IA);
    float PR = fmaf(2.0f, k2R + k3R, k1R);
    rhs2(tSE,tIA,b1,k4SE,k4IA,k4R);
    zSE = vfma(h6v, PSE + k4SE, zSE);
    zIA = vfma(h6v, PIA + k4IA, zIA);
    zR  = fmaf(h6v.x, PR + k4R, zR);
}

__device__ __forceinline__ float aload(const float* p) {
    return __hip_atomic_load(p, __ATOMIC_RELAXED, __HIP_MEMORY_SCOPE_AGENT);
}

// Gate: all 64 lanes verify comps 0..2 of float4 rows [0..n), then acquire.
__device__ __forceinline__ void gate3(const float4* rows, int n, int lane) {
    for (;;) {
        bool ok = true;
        for (int r = lane; r < n; r += 64) {
            const float* p = (const float*)(rows + r);
            ok &= (aload(p) > 0.0f) && (aload(p+1) > 0.0f) && (aload(p+2) > 0.0f);
        }
        if (__all(ok)) break;
        __builtin_amdgcn_s_sleep(2);
    }
    __builtin_amdgcn_fence(__ATOMIC_ACQUIRE, "agent");
}
// Gate for stride-8 6-comp Tsit5 rows [0..n).
__device__ __forceinline__ void gate6(const float* rowT, int n, int lane) {
    for (;;) {
        bool ok = true;
        for (int r = lane; r < n; r += 64) {
            const float* p = rowT + r * 8;
            ok &= (aload(p)>0.f) && (aload(p+1)>0.f) && (aload(p+2)>0.f)
               && (aload(p+3)>0.f) && (aload(p+4)>0.f) && (aload(p+5)>0.f);
        }
        if (__all(ok)) break;
        __builtin_amdgcn_s_sleep(2);
    }
    __builtin_amdgcn_fence(__ATOMIC_ACQUIRE, "agent");
}

__global__ __launch_bounds__(64, 1) void fused_kernel(
    const float* __restrict__ ts,
    const float* __restrict__ state_vec,
    const float* __restrict__ w_in, const float* __restrict__ b_in,
    const float* __restrict__ w_h,  const float* __restrict__ b_h,
    const float* __restrict__ w_out, const float* __restrict__ b_out,
    float* __restrict__ rowT, float4* __restrict__ rowC,
    float4* __restrict__ rowF,
    float* __restrict__ done_arr, float* __restrict__ out,
    Bounds B)
{
    int b    = blockIdx.x;
    int lane = threadIdx.x;

    if (b >= NCHUNK) {
        // ================= producer, then full burn =================
        int p = b - NCHUNK;
        float t0g = ts[0], hf = ts[1] - ts[0];
        float wi = w_in[lane], bi_ = b_in[lane];
        float bhh = b_h[lane], wo = w_out[lane];
        float bo = b_out[0];
        const float* __restrict__ wr = w_h + (lane << 6);
        float* rowCf = (float*)rowC;
        float* rowFf = (float*)rowF;

        for (int e = p; e < TTOTAL; e += NPROD) {
            float t; int kind, i = 0;
            if (e < NT5R * 6) { kind = 0;
                int row = e / 6, st = e - row * 6;
                t = t0g + (4.0f * row + 4.0f * g_cstage[st]) * hf;
            } else if (e < NT5R * 6 + 2 * 1023) {
                int idx = e - NT5R * 6; i = idx >> 1;
                if (idx & 1) { kind = 2; t = t0g + ((float)i + 0.5f) * hf; }
                else         { kind = 1; t = t0g + (float)i * hf; }
            } else { kind = 1; i = 1023; t = t0g + 1023.0f * hf; }

            float h1 = softplus_f(fmaf(wi, t, bi_));
            float acc = bhh;
#pragma unroll
            for (int k = 0; k < 64; ++k)
                acc = fmaf(wr[k], __shfl(h1, k, 64), acc);
            float h2 = softplus_f(acc);
            float pr = wo * h2;
#pragma unroll
            for (int off = 32; off > 0; off >>= 1)
                pr += __shfl_down(pr, off, 64);
            if (lane == 0) {
                float o  = pr + bo;
                float bb = 1.0f / (1.0f + expf(-1e-4f * o));   // in (0,1)
#define ASTORE(ptr) __hip_atomic_store((ptr), bb, __ATOMIC_RELAXED, \
                                       __HIP_MEMORY_SCOPE_AGENT)
                if (kind == 0) {
                    ASTORE(rowT + (e / 6) * 8 + (e % 6));
                } else if (kind == 1) {                 // bi[i]
                    if (i <= 1022) ASTORE(rowFf + i * 4 + 0);
                    if (i >= 1)    ASTORE(rowFf + (i - 1) * 4 + 2);
                    if (i >= 256) {
                        int d = i - 256;
                        if ((d & 3) == 0) {             // beta(256+4j)
                            int j = d >> 2;
                            if (j < ROWC_ALLOC) ASTORE(rowCf + j * 4 + 0);
                            if (j >= 1)         ASTORE(rowCf + (j - 1) * 4 + 2);
                        } else if ((d & 3) == 2) {      // beta(258+4j)
                            int j = (d - 2) >> 2;
                            if (j < ROWC_ALLOC) ASTORE(rowCf + j * 4 + 1);
                        }
                    }
                } else {                                // bh[i]
                    ASTORE(rowFf + i * 4 + 1);
                }
#undef ASTORE
            }
        }

        // full burn (r10-proven): keep clock/activity until integrators done
        float x[8];
#pragma unroll
        for (int j = 0; j < 8; ++j) x[j] = 1.0f + (float)(lane + j) * 1e-12f;
        for (int outer = 0; outer < BURN_MAX_POLLS; ++outer) {
            for (int i2 = 0; i2 < 40; ++i2) {
#pragma unroll
                for (int j = 0; j < 8; ++j)
                    x[j] = fmaf(x[j], 0.99999988f, 1e-9f);
            }
            float f = aload(done_arr + (lane & 31));
            if (__all(f == 1.0f)) break;
        }
        float r = 0.0f;
#pragma unroll
        for (int j = 0; j < 8; ++j) r += x[j];
        if (r == 123456.0f) done_arr[63] = r;
        return;
    }

    // ================= integrator block b =================
    int start = B.s[b];
    int end   = B.s[b + 1];
    int nf    = end - start;
    float hf  = ts[1] - ts[0];
    int nc    = start >> 2;           // starts are multiples of 4
    int nT    = imin(nc, 64);
    int nR    = nc - nT;              // RK4-h4 steps from t=256

    // z0 = softmax(state_vec) (lane 0 registers)
    v2f zSE, zIA; float zR;
    if (lane == 0) {
        float v[5], zz[5];
#pragma unroll
        for (int s = 0; s < 5; ++s) v[s] = state_vec[s];
        float m = v[0];
#pragma unroll
        for (int s = 1; s < 5; ++s) m = fmaxf(m, v[s]);
        float sum = 0.0f;
#pragma unroll
        for (int s = 0; s < 5; ++s) { zz[s] = expf(v[s] - m); sum += zz[s]; }
        float inv = 1.0f / sum;
#pragma unroll
        for (int s = 0; s < 5; ++s) zz[s] *= inv;
        zSE = (v2f){zz[0], zz[1]}; zIA = (v2f){zz[2], zz[3]}; zR = zz[4];
        if (b == 0) {
#pragma unroll
            for (int s = 0; s < 5; ++s) out[s] = zz[s];
        }
    }

    if (nf > 0) {
        // ---- Tsit5-h4 transient replay (gated, checkless) ----
        if (nT > 0) {
            gate6(rowT, nT, lane);
            if (lane == 0) {
                Tab2 T = make_tab2(4.0f * hf);
                float4 q0 = *(const float4*)(rowT);
                float2 s0 = *(const float2*)(rowT + 4);
                float4 q1 = *(const float4*)(rowT + 8);
                float2 s1 = *(const float2*)(rowT + 12);
                int i = 0;
                for (; i + 2 <= nT; i += 2) {
                    float bc[6] = {q0.x,q0.y,q0.z,q0.w,s0.x,s0.y};
                    q0 = *(const float4*)(rowT + (i + 2) * 8);
                    s0 = *(const float2*)(rowT + (i + 2) * 8 + 4);
                    t5_step(zSE, zIA, zR, T, bc);
                    float bd[6] = {q1.x,q1.y,q1.z,q1.w,s1.x,s1.y};
                    q1 = *(const float4*)(rowT + (i + 3) * 8);
                    s1 = *(const float2*)(rowT + (i + 3) * 8 + 4);
                    t5_step(zSE, zIA, zR, T, bd);
                }
                if (i < nT) {
                    float bc[6] = {q0.x,q0.y,q0.z,q0.w,s0.x,s0.y};
                    t5_step(zSE, zIA, zR, T, bc);
                }
            }
        }

        // ---- RK4-h4 post-peak replay (gated, checkless) ----
        if (nR > 0) {
            gate3(rowC, nR, lane);
            if (lane == 0) {
                v2f h2v = splat2(2.0f * hf), hv = splat2(4.0f * hf),
                    h6v = splat2(4.0f * hf / 6.0f);
                float4 c0 = rowC[0], c1 = rowC[1],
                       c2 = rowC[2], c3 = rowC[3];
                int j = 0;
                for (; j + 4 <= nR; j += 4) {
                    float4 u;
                    u = c0; c0 = rowC[j + 4];
                    rk4_step(zSE,zIA,zR,h2v,hv,h6v,u.x,u.y,u.z);
                    u = c1; c1 = rowC[j + 5];
                    rk4_step(zSE,zIA,zR,h2v,hv,h6v,u.x,u.y,u.z);
                    u = c2; c2 = rowC[j + 6];
                    rk4_step(zSE,zIA,zR,h2v,hv,h6v,u.x,u.y,u.z);
                    u = c3; c3 = rowC[j + 7];
                    rk4_step(zSE,zIA,zR,h2v,hv,h6v,u.x,u.y,u.z);
                }
                if (j < nR) { rk4_step(zSE,zIA,zR,h2v,hv,h6v,c0.x,c0.y,c0.z); j++; }
                if (j < nR) { rk4_step(zSE,zIA,zR,h2v,hv,h6v,c1.x,c1.y,c1.z); j++; }
                if (j < nR) { rk4_step(zSE,zIA,zR,h2v,hv,h6v,c2.x,c2.y,c2.z); j++; }
            }
        }

        // ---- fine RK4-h1 sweep (gated, checkless), store each interval ----
        gate3(rowF + start, nf, lane);
        if (lane == 0) {
            v2f h2v = splat2(0.5f * hf), hv = splat2(hf),
                h6v = splat2(hf * (1.0f / 6.0f));
            const float4* RF = rowF + start;
            float4 r0 = RF[0], r1 = RF[1], r2 = RF[2], r3 = RF[3];
            int i = 0;
#define FSTORE(ii) { \
            float* op = out + (size_t)(start + (ii) + 1) * 5; \
            op[0]=zSE.x; op[1]=zSE.y; op[2]=zIA.x; op[3]=zIA.y; op[4]=zR; }
            for (; i + 4 <= nf; i += 4) {
                float4 u;
                u = r0; r0 = RF[i + 4];
                rk4_step(zSE,zIA,zR,h2v,hv,h6v,u.x,u.y,u.z); FSTORE(i)
                u = r1; r1 = RF[i + 5];
                rk4_step(zSE,zIA,zR,h2v,hv,h6v,u.x,u.y,u.z); FSTORE(i + 1)
                u = r2; r2 = RF[i + 6];
                rk4_step(zSE,zIA,zR,h2v,hv,h6v,u.x,u.y,u.z); FSTORE(i + 2)
                u = r3; r3 = RF[i + 7];
                rk4_step(zSE,zIA,zR,h2v,hv,h6v,u.x,u.y,u.z); FSTORE(i + 3)
            }
            if (i < nf) { rk4_step(zSE,zIA,zR,h2v,hv,h6v,r0.x,r0.y,r0.z);
                          FSTORE(i) i++; }
            if (i < nf) { rk4_step(zSE,zIA,zR,h2v,hv,h6v,r1.x,r1.y,r1.z);
                          FSTORE(i) i++; }
            if (i < nf) { rk4_step(zSE,zIA,zR,h2v,hv,h6v,r2.x,r2.y,r2.z);
                          FSTORE(i) i++; }
#undef FSTORE
        }
    }

    if (lane == 0)
        __hip_atomic_store(done_arr + b, 1.0f, __ATOMIC_RELAXED,
                           __HIP_MEMORY_SCOPE_AGENT);
}

extern "C" void kernel_launch(void* const* d_in, const int* in_sizes, int n_in,
                              void* d_out, int out_size, void* d_ws, size_t ws_size,
                              hipStream_t stream)
{
    // 0 y0_ignored(5) 1 ts(1024) 2 state_vec(5) 3 w_in(64) 4 b_in(64)
    // 5 w_h(4096) 6 b_h(64) 7 w_out(64) 8 b_out(1) 9 scales(5)  [all f32]
    const float* ts        = (const float*)d_in[1];
    const float* state_vec = (const float*)d_in[2];
    const float* w_in      = (const float*)d_in[3];
    const float* b_in      = (const float*)d_in[4];
    const float* w_h       = (const float*)d_in[5];
    const float* b_h       = (const float*)d_in[6];
    const float* w_out     = (const float*)d_in[7];
    const float* b_out     = (const float*)d_in[8];
    float* out = (float*)d_out;

    int n_int = in_sizes[1] - 1;                  // 1023

    // Balanced bounds, cycle units: T5-h4 75/interval (<=256), RK4-h4
    // 45/interval (>256), fine RK4-h1 200/interval. Grid: multiples of 4.
    const float cT = 75.f, cR = 45.f, cF = 200.f;
    auto costR = [&](float s) {
        float a = s < 256.f ? s : 256.f;
        float c = s > 256.f ? s - 256.f : 0.f;
        return cT * a + cR * c;
    };
    auto nextS = [&](float D, int s) {
        float f = (D - costR((float)s)) / cF;
        int fi = ((int)(f / 4.f)) * 4;
        if (fi < 4) fi = 4;
        int s2 = s + fi;
        if (s2 > n_int) s2 = n_int;
        return s2;
    };
    auto cover = [&](float D) {
        int s = 0;
        for (int bb = 0; bb < NCHUNK; ++bb) s = nextS(D, s);
        return s;
    };
    float lo = 800.f, hi = 300000.f;
    for (int it = 0; it < 48; ++it) {
        float mid = 0.5f * (lo + hi);
        if (cover(mid) >= n_int) hi = mid; else lo = mid;
    }
    float D = hi;
    Bounds B;
    {
        int s = 0; B.s[0] = 0;
        for (int bb = 0; bb < NCHUNK; ++bb) {
            s = nextS(D, s);
            B.s[bb + 1] = s;
        }
        B.s[NCHUNK] = n_int;
    }

    // Workspace (floats): done_arr 64 | rowT 68*8 | rowC 200*4 | rowF 1032*4
    float* done_arr = (float*)d_ws;
    float* rowT     = done_arr + 64;
    float4* rowC    = (float4*)(rowT + (size_t)ROWT_ALLOC * 8);
    float4* rowF    = rowC + ROWC_ALLOC;

    fused_kernel<<<NTOTAL, 64, 0, stream>>>(
        ts, state_vec, w_in, b_in, w_h, b_h, w_out, b_out,
        rowT, rowC, rowF, done_arr, out, B);
}